// Round 5
// baseline (1067.266 us; speedup 1.0000x reference)
//
#include <hip/hip_runtime.h>
#include <math.h>

#define B 4
#define NPTS 300000
#define G 15
#define G3 3375
#define SCENE_FLOATS (B*12*G3)   // 162000
#define NREP 8
#define NB_TAIL 256              // blocks in fused tail kernel

__device__ __forceinline__ float eluf(float v) {
    return v > 0.0f ? v : __expf(v) - 1.0f;
}

// ---------------------------------------------------------------------------
// Stage 1: per-point features -> MLP (weights via uniform/scalar loads) ->
// filtered scatter-max into one of NREP replicated grids.
// Monotonic-filter: a plain (stale-ok) read is a lower bound of the final
// value, so v <= read  =>  skip the atomic safely.
// ---------------------------------------------------------------------------
__global__ __launch_bounds__(256)
void point_kernel(const float* __restrict__ P0,   // inputs  (set 0)
                  const float* __restrict__ P1,   // goals   (set 1)
                  const float* __restrict__ P2,   // backgrounds (set 2)
                  const float* __restrict__ W1, const float* __restrict__ b1,
                  const float* __restrict__ W2, const float* __restrict__ b2,
                  const float* __restrict__ W3, const float* __restrict__ b3,
                  float* __restrict__ scenesR, int nrep)
{
    int b   = blockIdx.y;
    int set = blockIdx.z;
    const float* P = (set == 0) ? P0 : ((set == 1) ? P1 : P2);

    int idx = blockIdx.x * 256 + threadIdx.x;
    if (idx >= NPTS) return;

    const float* p = P + ((size_t)b * NPTS + idx) * 3;
    float px = p[0], py = p[1], pz = p[2];

    const float HI = 14.9999f;  // GZ - 1e-4
    float cx = floorf(fminf(fmaxf(px, 0.0f), HI));
    float cy = floorf(fminf(fmaxf(py, 0.0f), HI));
    float cz = floorf(fminf(fmaxf(pz, 0.0f), HI));

    float x[12];
    x[0] = px - (cx + 0.5f); x[1] = py - (cy + 0.5f); x[2] = pz - (cz + 0.5f);
    x[3] = px - cx;          x[4] = py - cy;          x[5] = pz - cz;
    x[6] = px - (cx + 1.0f); x[7] = py - (cy + 1.0f); x[8] = pz - (cz + 1.0f);
    x[9]  = sqrtf(x[0]*x[0] + x[1]*x[1] + x[2]*x[2]);
    x[10] = sqrtf(x[3]*x[3] + x[4]*x[4] + x[5]*x[5]);
    x[11] = sqrtf(x[6]*x[6] + x[7]*x[7] + x[8]*x[8]);

    // wave-uniform weight indices -> s_load via constant cache, SGPR operands
    float h1[16];
#pragma unroll
    for (int j = 0; j < 16; ++j) {
        float s = b1[j];
#pragma unroll
        for (int k = 0; k < 12; ++k) s = fmaf(x[k], W1[k*16 + j], s);
        h1[j] = eluf(s);
    }
    float h2[16];
#pragma unroll
    for (int j = 0; j < 16; ++j) {
        float s = b2[j];
#pragma unroll
        for (int k = 0; k < 16; ++k) s = fmaf(h1[k], W2[k*16 + j], s);
        h2[j] = eluf(s);
    }
    float o[4];
#pragma unroll
    for (int j = 0; j < 4; ++j) {
        float s = b3[j];
#pragma unroll
        for (int k = 0; k < 16; ++k) s = fmaf(h2[k], W3[k*4 + j], s);
        o[j] = s;
    }

    int cell = (((int)cx) * G + (int)cy) * G + (int)cz;
    int rep  = blockIdx.x & (nrep - 1);
    float* dstf = scenesR + (size_t)rep * SCENE_FLOATS
                          + (size_t)(b * 12 + set * 4) * G3 + cell;
#pragma unroll
    for (int c = 0; c < 4; ++c) {
        float v = o[c];
        if (v > 0.0f) {
            float cur = dstf[c * G3];           // stale-ok lower bound
            if (v > cur)
                atomicMax((unsigned*)(dstf + c * G3), __float_as_uint(v));
        }
    }
}

// ---------------------------------------------------------------------------
// Device-scope grid barrier (per-phase counter slot, no reset needed).
// All NB_TAIL blocks are co-resident (1024 waves << 8192 device capacity).
// __threadfence() = agent-scope fence -> compiler emits the gfx950 L2
// writeback/invalidate ops, making plain cross-XCD stores/loads visible.
// ---------------------------------------------------------------------------
__device__ __forceinline__ void grid_barrier(unsigned* cnt, int nb) {
    __syncthreads();
    __threadfence();   // release: drain + write back this XCD's dirty lines
    if (threadIdx.x == 0) {
        __hip_atomic_fetch_add(cnt, 1u, __ATOMIC_ACQ_REL, __HIP_MEMORY_SCOPE_AGENT);
        while (__hip_atomic_load(cnt, __ATOMIC_ACQUIRE, __HIP_MEMORY_SCOPE_AGENT)
               < (unsigned)nb) {
            __builtin_amdgcn_s_sleep(1);
        }
    }
    __syncthreads();
    __threadfence();   // acquire: invalidate stale lines before new reads
}

// ---------------------------------------------------------------------------
// Fused tail: replica max-reduce -> conv1(+stats) -> 6x [BN+ELU+conv](+stats)
// -> final BN+ELU -> d_out.   256 blocks x 256 threads, 8 grid barriers.
// Conv phases: block = (b,co,od); threads = (ciq,oh,ow).
// ---------------------------------------------------------------------------
__global__ __launch_bounds__(256)
void tail_kernel(const float* __restrict__ scenesR, int nrep,
                 float* __restrict__ scenes,
                 const float* __restrict__ conv1_w, const float* __restrict__ conv1_b,
                 const float* __restrict__ bn1_g,   const float* __restrict__ bn1_b,
                 const float* __restrict__ convs_w, const float* __restrict__ convs_b,
                 const float* __restrict__ bns_g,   const float* __restrict__ bns_b,
                 float* __restrict__ yA, float* __restrict__ yB,
                 float* __restrict__ stats,          // 7*16 floats, pre-zeroed
                 unsigned* __restrict__ bar,         // 8 counters, pre-zeroed
                 float* __restrict__ outp)
{
    __shared__ float slab[8 * 5 * 144];   // [ci][kd][12][12] zero-padded
    __shared__ float sscale[8], sshift[8];
    __shared__ float sred[256];

    const int bx  = blockIdx.x;
    const int tid = threadIdx.x;
    const int od = bx & 7, co = (bx >> 3) & 7, b = bx >> 6;
    const int ow = tid & 7, oh = (tid >> 3) & 7, ciq = tid >> 6;

    // ---- phase 0: reduce replicas -> scenes -------------------------------
    for (int t = bx * 256 + tid; t < SCENE_FLOATS; t += NB_TAIL * 256) {
        float m = 0.0f;
        for (int r = 0; r < nrep; ++r)
            m = fmaxf(m, scenesR[(size_t)r * SCENE_FLOATS + t]);
        scenes[t] = m;
    }
    grid_barrier(bar + 0, NB_TAIL);

    // ---- phase 1: conv1 (stride 2) + stats0 -------------------------------
    {
        float s = 0.0f;
        for (int cin = 0; cin < 3; ++cin) {
            int ci = ciq * 3 + cin;
            const float* sc = scenes + (size_t)(b * 12 + ci) * G3;
            const float* wc = conv1_w + (size_t)(co * 12 + ci) * 125;
#pragma unroll
            for (int kd = 0; kd < 5; ++kd) {
                int id = od * 2 - 2 + kd;
                if ((unsigned)id >= (unsigned)G) continue;   // block-uniform
#pragma unroll
                for (int kh = 0; kh < 5; ++kh) {
                    int ih = oh * 2 - 2 + kh;
                    bool hok = (unsigned)ih < (unsigned)G;
#pragma unroll
                    for (int kw = 0; kw < 5; ++kw) {
                        int iw = ow * 2 - 2 + kw;
                        if (hok && (unsigned)iw < (unsigned)G)
                            s = fmaf(sc[(id * G + ih) * G + iw],
                                     wc[kd*25 + kh*5 + kw], s);
                    }
                }
            }
        }
        sred[tid] = s;
        __syncthreads();
        if (tid < 64) {
            float tot = sred[tid] + sred[64+tid] + sred[128+tid] + sred[192+tid]
                      + conv1_b[co];
            yA[(size_t)(b * 8 + co) * 512 + od * 64 + tid] = tot;
            float sum = tot, sq = tot * tot;
#pragma unroll
            for (int o = 32; o > 0; o >>= 1) {
                sum += __shfl_down(sum, o, 64);
                sq  += __shfl_down(sq,  o, 64);
            }
            if (tid == 0) {
                atomicAdd(&stats[co], sum);        // FIX (R4 bug): was stats[0]
                atomicAdd(&stats[8 + co], sq);     // FIX (R4 bug): was stats[8]
            }
        }
    }

    // ---- phases 2..7: six BN+ELU+conv(stride1) layers ---------------------
    const float* cur = yA;
    float* nxt = yB;
    for (int li = 1; li <= 6; ++li) {
        grid_barrier(bar + li, NB_TAIL);

        const float* g   = (li == 1) ? bn1_g : (bns_g + (li - 2) * 8);
        const float* bet = (li == 1) ? bn1_b : (bns_b + (li - 2) * 8);
        const float* sin = stats + (li - 1) * 16;
        const float* w   = convs_w + (size_t)(li - 1) * 8000;

        if (tid < 8) {
            float S = sin[tid], Q = sin[8 + tid];
            float m  = S * (1.0f / 2048.0f);
            float vv = Q * (1.0f / 2048.0f) - m * m;
            float rs = rsqrtf(vv + 1e-5f);
            float sc = g[tid] * rs;
            sscale[tid] = sc;
            sshift[tid] = bet[tid] - m * sc;
        }
        __syncthreads();

        for (int s = tid; s < 5760; s += 256) {
            int ci = s / 720; int r = s % 720;
            int kd = r / 144; int r2 = r % 144;
            int ph = r2 / 12, pw = r2 % 12;
            int id = od - 2 + kd, ih = ph - 2, iw = pw - 2;
            float v = 0.0f;
            if ((unsigned)id < 8u && (unsigned)ih < 8u && (unsigned)iw < 8u) {
                float raw = cur[(size_t)(b * 8 + ci) * 512 + id * 64 + ih * 8 + iw];
                float t = fmaf(raw, sscale[ci], sshift[ci]);
                v = t > 0.0f ? t : __expf(t) - 1.0f;
            }
            slab[s] = v;
        }
        __syncthreads();

        float s = 0.0f;
#pragma unroll
        for (int c2 = 0; c2 < 2; ++c2) {
            int ci = ciq * 2 + c2;
            const float* sl = slab + ci * 720;
            const float* wc = w + (size_t)(co * 8 + ci) * 125;
#pragma unroll
            for (int kd = 0; kd < 5; ++kd) {
#pragma unroll
                for (int kh = 0; kh < 5; ++kh) {
                    const float* row = sl + kd * 144 + (oh + kh) * 12 + ow;
                    const float* wr = wc + kd * 25 + kh * 5;
#pragma unroll
                    for (int kw = 0; kw < 5; ++kw) s = fmaf(row[kw], wr[kw], s);
                }
            }
        }
        sred[tid] = s;
        __syncthreads();
        if (tid < 64) {
            float tot = sred[tid] + sred[64+tid] + sred[128+tid] + sred[192+tid]
                      + convs_b[(li - 1) * 8 + co];
            nxt[(size_t)(b * 8 + co) * 512 + od * 64 + tid] = tot;
            float sum = tot, sq = tot * tot;
#pragma unroll
            for (int o = 32; o > 0; o >>= 1) {
                sum += __shfl_down(sum, o, 64);
                sq  += __shfl_down(sq,  o, 64);
            }
            if (tid == 0) {
                atomicAdd(&stats[li * 16 + co], sum);
                atomicAdd(&stats[li * 16 + 8 + co], sq);
            }
        }
        __syncthreads();
        const float* tmp = cur; cur = nxt; nxt = (float*)tmp;
    }

    // ---- final BN + ELU -> out -------------------------------------------
    grid_barrier(bar + 7, NB_TAIL);
    int i = bx * 256 + tid;
    if (i < 16384) {
        int c = (i >> 9) & 7;
        float S = stats[6 * 16 + c], Q = stats[6 * 16 + 8 + c];
        float m  = S * (1.0f / 2048.0f);
        float vv = Q * (1.0f / 2048.0f) - m * m;
        float rs = rsqrtf(vv + 1e-5f);
        float sc = bns_g[5 * 8 + c] * rs;
        float sh = bns_b[5 * 8 + c] - m * sc;
        float t = fmaf(cur[i], sc, sh);
        outp[i] = t > 0.0f ? t : __expf(t) - 1.0f;
    }
}

// ---------------------------------------------------------------------------
extern "C" void kernel_launch(void* const* d_in, const int* in_sizes, int n_in,
                              void* d_out, int out_size, void* d_ws, size_t ws_size,
                              hipStream_t stream)
{
    const float* goals       = (const float*)d_in[0];
    const float* inputs      = (const float*)d_in[1];
    const float* backgrounds = (const float*)d_in[2];
    const float* W1 = (const float*)d_in[3];
    const float* b1 = (const float*)d_in[4];
    const float* W2 = (const float*)d_in[5];
    const float* b2 = (const float*)d_in[6];
    const float* W3 = (const float*)d_in[7];
    const float* b3 = (const float*)d_in[8];
    const float* conv1_w = (const float*)d_in[9];
    const float* conv1_b = (const float*)d_in[10];
    const float* bn1_g   = (const float*)d_in[11];
    const float* bn1_b   = (const float*)d_in[12];
    const float* convs_w = (const float*)d_in[13];
    const float* convs_b = (const float*)d_in[14];
    const float* bns_g   = (const float*)d_in[15];
    const float* bns_b   = (const float*)d_in[16];

    const size_t need8 = ((size_t)NREP * SCENE_FLOATS + SCENE_FLOATS
                          + 2 * 16384 + 112 + 16) * 4;
    int nrep = (ws_size >= need8) ? NREP : 1;

    float* wsp     = (float*)d_ws;
    float* scenesR = wsp;                                   // nrep * 162000
    float* scenes  = scenesR + (size_t)nrep * SCENE_FLOATS; // 162000
    float* yA      = scenes + SCENE_FLOATS;                 // 16384
    float* yB      = yA + 16384;                            // 16384
    float* stats   = yB + 16384;                            // 7*16 floats
    unsigned* bar  = (unsigned*)(stats + 7 * 16);           // 8 counters

    hipMemsetAsync(scenesR, 0, (size_t)nrep * SCENE_FLOATS * sizeof(float), stream);
    hipMemsetAsync(stats, 0, (7 * 16) * sizeof(float) + 8 * sizeof(unsigned), stream);

    dim3 pgrid((NPTS + 255) / 256, B, 3);
    point_kernel<<<pgrid, 256, 0, stream>>>(inputs, goals, backgrounds,
                                            W1, b1, W2, b2, W3, b3, scenesR, nrep);

    tail_kernel<<<NB_TAIL, 256, 0, stream>>>(scenesR, nrep, scenes,
                                             conv1_w, conv1_b, bn1_g, bn1_b,
                                             convs_w, convs_b, bns_g, bns_b,
                                             yA, yB, stats, bar, (float*)d_out);
}

// Round 6
// 694.876 us; speedup vs baseline: 1.5359x; 1.5359x over previous
//
#include <hip/hip_runtime.h>
#include <math.h>

#define B 4
#define NPTS 300000
#define G 15
#define G3 3375
#define CELLS4 (4*G3)            // 13500 floats: one (b,set) private grid
#define SCENE_FLOATS (B*12*G3)   // 162000
#define NB_TAIL 256              // blocks in fused tail kernel

__device__ __forceinline__ float eluf(float v) {
    return v > 0.0f ? v : __expf(v) - 1.0f;
}

// ---------------------------------------------------------------------------
// Stage 1: per-point features -> MLP (weights via uniform/scalar loads) ->
// LDS-privatized scatter-max (ds_max_u32, zero global atomics) ->
// coalesced uint4 flush into partials[(set*4+b)*nsub + sub][13500].
// grid: (nsub, B, 3) x 512 threads. 54 KB LDS -> 2 blocks/CU.
// ---------------------------------------------------------------------------
__global__ __launch_bounds__(512)
void point_kernel(const float* __restrict__ P0,   // inputs  (set 0)
                  const float* __restrict__ P1,   // goals   (set 1)
                  const float* __restrict__ P2,   // backgrounds (set 2)
                  const float* __restrict__ W1, const float* __restrict__ b1,
                  const float* __restrict__ W2, const float* __restrict__ b2,
                  const float* __restrict__ W3, const float* __restrict__ b3,
                  float* __restrict__ partials, int nsub, int ppb)
{
    __shared__ unsigned gridS[CELLS4];   // 54000 B
    const int tid = threadIdx.x;
    const int sub = blockIdx.x, b = blockIdx.y, set = blockIdx.z;

    for (int i = tid; i < CELLS4; i += 512) gridS[i] = 0u;
    __syncthreads();

    const float* P  = (set == 0) ? P0 : ((set == 1) ? P1 : P2);
    const float* Pb = P + (size_t)b * NPTS * 3;
    const int start = sub * ppb;
    const int end   = min(NPTS, start + ppb);
    const float HI  = 14.9999f;   // GZ - 1e-4

    for (int idx = start + tid; idx < end; idx += 512) {
        float px = Pb[idx*3 + 0], py = Pb[idx*3 + 1], pz = Pb[idx*3 + 2];

        float cx = floorf(fminf(fmaxf(px, 0.0f), HI));
        float cy = floorf(fminf(fmaxf(py, 0.0f), HI));
        float cz = floorf(fminf(fmaxf(pz, 0.0f), HI));

        float x[12];
        x[0] = px - (cx + 0.5f); x[1] = py - (cy + 0.5f); x[2] = pz - (cz + 0.5f);
        x[3] = px - cx;          x[4] = py - cy;          x[5] = pz - cz;
        x[6] = px - (cx + 1.0f); x[7] = py - (cy + 1.0f); x[8] = pz - (cz + 1.0f);
        x[9]  = sqrtf(x[0]*x[0] + x[1]*x[1] + x[2]*x[2]);
        x[10] = sqrtf(x[3]*x[3] + x[4]*x[4] + x[5]*x[5]);
        x[11] = sqrtf(x[6]*x[6] + x[7]*x[7] + x[8]*x[8]);

        // wave-uniform weight indices -> s_load via constant cache
        float h1[16];
#pragma unroll
        for (int j = 0; j < 16; ++j) {
            float s = b1[j];
#pragma unroll
            for (int k = 0; k < 12; ++k) s = fmaf(x[k], W1[k*16 + j], s);
            h1[j] = eluf(s);
        }
        float h2[16];
#pragma unroll
        for (int j = 0; j < 16; ++j) {
            float s = b2[j];
#pragma unroll
            for (int k = 0; k < 16; ++k) s = fmaf(h1[k], W2[k*16 + j], s);
            h2[j] = eluf(s);
        }
        int cell = (((int)cx) * G + (int)cy) * G + (int)cz;
#pragma unroll
        for (int j = 0; j < 4; ++j) {
            float s = b3[j];
#pragma unroll
            for (int k = 0; k < 16; ++k) s = fmaf(h2[k], W3[k*4 + j], s);
            if (s > 0.0f)   // grid floor is 0; positive floats order like uints
                atomicMax(&gridS[j * G3 + cell], __float_as_uint(s));
        }
    }
    __syncthreads();

    // coalesced 16B flush (CELLS4*4 = 54000 B, 16B-aligned per block)
    uint4* dst = (uint4*)(partials + (size_t)((set * 4 + b) * nsub + sub) * CELLS4);
    const uint4* src = (const uint4*)gridS;
    for (int t = tid; t < CELLS4 / 4; t += 512) dst[t] = src[t];
}

// ---------------------------------------------------------------------------
// Device-scope grid barrier, cheap form: release fence once at arrival,
// RELAXED polling (no per-poll cache invalidates), single acquire fence.
// All NB_TAIL blocks co-resident (1024 waves << capacity).
// ---------------------------------------------------------------------------
__device__ __forceinline__ void grid_barrier(unsigned* cnt, int nb) {
    __syncthreads();   // all waves' stores drained to L2 (wg fence)
    if (threadIdx.x == 0) {
        __builtin_amdgcn_fence(__ATOMIC_RELEASE, "agent");   // wb this XCD's L2
        __hip_atomic_fetch_add(cnt, 1u, __ATOMIC_RELAXED, __HIP_MEMORY_SCOPE_AGENT);
        while (__hip_atomic_load(cnt, __ATOMIC_RELAXED, __HIP_MEMORY_SCOPE_AGENT)
               < (unsigned)nb) {
            __builtin_amdgcn_s_sleep(4);
        }
    }
    __syncthreads();
    __builtin_amdgcn_fence(__ATOMIC_ACQUIRE, "agent");       // one-time inv
}

// ---------------------------------------------------------------------------
// Fused tail: partial max-reduce -> conv1(+stats) -> 6x [BN+ELU+conv](+stats)
// -> final BN+ELU -> d_out.   256 blocks x 256 threads, 8 grid barriers.
// Conv phases: block = (b,co,od); threads = (ciq,oh,ow).
// ---------------------------------------------------------------------------
__global__ __launch_bounds__(256)
void tail_kernel(const float* __restrict__ partials, int nsub,
                 float* __restrict__ scenes,
                 const float* __restrict__ conv1_w, const float* __restrict__ conv1_b,
                 const float* __restrict__ bn1_g,   const float* __restrict__ bn1_b,
                 const float* __restrict__ convs_w, const float* __restrict__ convs_b,
                 const float* __restrict__ bns_g,   const float* __restrict__ bns_b,
                 float* __restrict__ yA, float* __restrict__ yB,
                 float* __restrict__ stats,          // 7*16 floats, pre-zeroed
                 unsigned* __restrict__ bar,         // 8 counters, pre-zeroed
                 float* __restrict__ outp)
{
    __shared__ float slab[8 * 5 * 144];   // [ci][kd][12][12] zero-padded
    __shared__ float sscale[8], sshift[8];
    __shared__ float sred[256];

    const int bx  = blockIdx.x;
    const int tid = threadIdx.x;
    const int od = bx & 7, co = (bx >> 3) & 7, b = bx >> 6;
    const int ow = tid & 7, oh = (tid >> 3) & 7, ciq = tid >> 6;

    // ---- phase 0: max-reduce partials -> scenes ---------------------------
    for (int t = bx * 256 + tid; t < SCENE_FLOATS; t += NB_TAIL * 256) {
        int pairIdx = t / CELLS4;          // set*4 + b
        int j       = t % CELLS4;          // channel*G3 + cell
        const float* p = partials + (size_t)pairIdx * nsub * CELLS4 + j;
        float m = 0.0f;
        for (int k = 0; k < nsub; ++k) m = fmaxf(m, p[(size_t)k * CELLS4]);
        int sb = pairIdx >> 2, bb = pairIdx & 3;
        scenes[(size_t)(bb * 12 + sb * 4) * G3 + j] = m;
    }
    grid_barrier(bar + 0, NB_TAIL);

    // ---- phase 1: conv1 (stride 2) + stats0 -------------------------------
    {
        float s = 0.0f;
        for (int cin = 0; cin < 3; ++cin) {
            int ci = ciq * 3 + cin;
            const float* sc = scenes + (size_t)(b * 12 + ci) * G3;
            const float* wc = conv1_w + (size_t)(co * 12 + ci) * 125;
#pragma unroll
            for (int kd = 0; kd < 5; ++kd) {
                int id = od * 2 - 2 + kd;
                if ((unsigned)id >= (unsigned)G) continue;   // block-uniform
#pragma unroll
                for (int kh = 0; kh < 5; ++kh) {
                    int ih = oh * 2 - 2 + kh;
                    bool hok = (unsigned)ih < (unsigned)G;
#pragma unroll
                    for (int kw = 0; kw < 5; ++kw) {
                        int iw = ow * 2 - 2 + kw;
                        if (hok && (unsigned)iw < (unsigned)G)
                            s = fmaf(sc[(id * G + ih) * G + iw],
                                     wc[kd*25 + kh*5 + kw], s);
                    }
                }
            }
        }
        sred[tid] = s;
        __syncthreads();
        if (tid < 64) {
            float tot = sred[tid] + sred[64+tid] + sred[128+tid] + sred[192+tid]
                      + conv1_b[co];
            yA[(size_t)(b * 8 + co) * 512 + od * 64 + tid] = tot;
            float sum = tot, sq = tot * tot;
#pragma unroll
            for (int o = 32; o > 0; o >>= 1) {
                sum += __shfl_down(sum, o, 64);
                sq  += __shfl_down(sq,  o, 64);
            }
            if (tid == 0) {
                atomicAdd(&stats[co], sum);
                atomicAdd(&stats[8 + co], sq);
            }
        }
    }

    // ---- phases 2..7: six BN+ELU+conv(stride1) layers ---------------------
    const float* cur = yA;
    float* nxt = yB;
    for (int li = 1; li <= 6; ++li) {
        grid_barrier(bar + li, NB_TAIL);

        const float* g   = (li == 1) ? bn1_g : (bns_g + (li - 2) * 8);
        const float* bet = (li == 1) ? bn1_b : (bns_b + (li - 2) * 8);
        const float* sin = stats + (li - 1) * 16;
        const float* w   = convs_w + (size_t)(li - 1) * 8000;

        if (tid < 8) {
            float S = sin[tid], Q = sin[8 + tid];
            float m  = S * (1.0f / 2048.0f);
            float vv = Q * (1.0f / 2048.0f) - m * m;
            float rs = rsqrtf(vv + 1e-5f);
            float sc = g[tid] * rs;
            sscale[tid] = sc;
            sshift[tid] = bet[tid] - m * sc;
        }
        __syncthreads();

        for (int s = tid; s < 5760; s += 256) {
            int ci = s / 720; int r = s % 720;
            int kd = r / 144; int r2 = r % 144;
            int ph = r2 / 12, pw = r2 % 12;
            int id = od - 2 + kd, ih = ph - 2, iw = pw - 2;
            float v = 0.0f;
            if ((unsigned)id < 8u && (unsigned)ih < 8u && (unsigned)iw < 8u) {
                float raw = cur[(size_t)(b * 8 + ci) * 512 + id * 64 + ih * 8 + iw];
                float t = fmaf(raw, sscale[ci], sshift[ci]);
                v = t > 0.0f ? t : __expf(t) - 1.0f;
            }
            slab[s] = v;
        }
        __syncthreads();

        float s = 0.0f;
#pragma unroll
        for (int c2 = 0; c2 < 2; ++c2) {
            int ci = ciq * 2 + c2;
            const float* sl = slab + ci * 720;
            const float* wc = w + (size_t)(co * 8 + ci) * 125;
#pragma unroll
            for (int kd = 0; kd < 5; ++kd) {
#pragma unroll
                for (int kh = 0; kh < 5; ++kh) {
                    const float* row = sl + kd * 144 + (oh + kh) * 12 + ow;
                    const float* wr = wc + kd * 25 + kh * 5;
#pragma unroll
                    for (int kw = 0; kw < 5; ++kw) s = fmaf(row[kw], wr[kw], s);
                }
            }
        }
        sred[tid] = s;
        __syncthreads();
        if (tid < 64) {
            float tot = sred[tid] + sred[64+tid] + sred[128+tid] + sred[192+tid]
                      + convs_b[(li - 1) * 8 + co];
            nxt[(size_t)(b * 8 + co) * 512 + od * 64 + tid] = tot;
            float sum = tot, sq = tot * tot;
#pragma unroll
            for (int o = 32; o > 0; o >>= 1) {
                sum += __shfl_down(sum, o, 64);
                sq  += __shfl_down(sq,  o, 64);
            }
            if (tid == 0) {
                atomicAdd(&stats[li * 16 + co], sum);
                atomicAdd(&stats[li * 16 + 8 + co], sq);
            }
        }
        __syncthreads();
        const float* tmp = cur; cur = nxt; nxt = (float*)tmp;
    }

    // ---- final BN + ELU -> out -------------------------------------------
    grid_barrier(bar + 7, NB_TAIL);
    int i = bx * 256 + tid;
    if (i < 16384) {
        int c = (i >> 9) & 7;
        float S = stats[6 * 16 + c], Q = stats[6 * 16 + 8 + c];
        float m  = S * (1.0f / 2048.0f);
        float vv = Q * (1.0f / 2048.0f) - m * m;
        float rs = rsqrtf(vv + 1e-5f);
        float sc = bns_g[5 * 8 + c] * rs;
        float sh = bns_b[5 * 8 + c] - m * sc;
        float t = fmaf(cur[i], sc, sh);
        outp[i] = t > 0.0f ? t : __expf(t) - 1.0f;
    }
}

// ---------------------------------------------------------------------------
extern "C" void kernel_launch(void* const* d_in, const int* in_sizes, int n_in,
                              void* d_out, int out_size, void* d_ws, size_t ws_size,
                              hipStream_t stream)
{
    const float* goals       = (const float*)d_in[0];
    const float* inputs      = (const float*)d_in[1];
    const float* backgrounds = (const float*)d_in[2];
    const float* W1 = (const float*)d_in[3];
    const float* b1 = (const float*)d_in[4];
    const float* W2 = (const float*)d_in[5];
    const float* b2 = (const float*)d_in[6];
    const float* W3 = (const float*)d_in[7];
    const float* b3 = (const float*)d_in[8];
    const float* conv1_w = (const float*)d_in[9];
    const float* conv1_b = (const float*)d_in[10];
    const float* bn1_g   = (const float*)d_in[11];
    const float* bn1_b   = (const float*)d_in[12];
    const float* convs_w = (const float*)d_in[13];
    const float* convs_b = (const float*)d_in[14];
    const float* bns_g   = (const float*)d_in[15];
    const float* bns_b   = (const float*)d_in[16];

    // tier nsub against workspace: partials = 12*nsub*13500 floats
    const size_t fixed_floats = SCENE_FLOATS + 2 * 16384 + 7 * 16 + 8 + 64;
    int nsub = 5;
    const int tiers[4] = {42, 21, 10, 5};
    for (int i = 0; i < 4; ++i) {
        size_t need = ((size_t)12 * tiers[i] * CELLS4 + fixed_floats) * 4;
        if (ws_size >= need) { nsub = tiers[i]; break; }
    }
    const int ppb = (NPTS + nsub - 1) / nsub;

    float* wsp      = (float*)d_ws;
    float* partials = wsp;                                      // 12*nsub*13500
    float* scenes   = partials + (size_t)12 * nsub * CELLS4;    // 162000
    float* yA       = scenes + SCENE_FLOATS;                    // 16384
    float* yB       = yA + 16384;                               // 16384
    float* stats    = yB + 16384;                               // 7*16
    unsigned* bar   = (unsigned*)(stats + 7 * 16);              // 8 counters

    // only stats + barrier counters need zeroing (partials fully overwritten)
    hipMemsetAsync(stats, 0, (7 * 16) * sizeof(float) + 8 * sizeof(unsigned), stream);

    dim3 pgrid(nsub, B, 3);
    point_kernel<<<pgrid, 512, 0, stream>>>(inputs, goals, backgrounds,
                                            W1, b1, W2, b2, W3, b3,
                                            partials, nsub, ppb);

    tail_kernel<<<NB_TAIL, 256, 0, stream>>>(partials, nsub, scenes,
                                             conv1_w, conv1_b, bn1_g, bn1_b,
                                             convs_w, convs_b, bns_g, bns_b,
                                             yA, yB, stats, bar, (float*)d_out);
}

// Round 7
// 579.384 us; speedup vs baseline: 1.8421x; 1.1993x over previous
//
#include <hip/hip_runtime.h>
#include <math.h>

#define B 4
#define NPTS 300000
#define G 15
#define G3 3375
#define SCENE_FLOATS (B*12*G3)   // 162000
#define NREP 8
#define NB_TAIL 256              // blocks in fused tail kernel

__device__ __forceinline__ float eluf(float v) {
    return v > 0.0f ? v : __expf(v) - 1.0f;
}

// ---------------------------------------------------------------------------
// Stage 1 (R3-proven): per-point features -> straight-line MLP (weights via
// wave-uniform s_loads) -> direct atomicMax scatter into one of NREP
// replicated grids. One point per thread, no loop: 24 VGPR, no spill.
// grid: (1172, B, 3) x 256.
// ---------------------------------------------------------------------------
__global__ __launch_bounds__(256)
void point_kernel(const float* __restrict__ P0,   // inputs  (set 0)
                  const float* __restrict__ P1,   // goals   (set 1)
                  const float* __restrict__ P2,   // backgrounds (set 2)
                  const float* __restrict__ W1, const float* __restrict__ b1,
                  const float* __restrict__ W2, const float* __restrict__ b2,
                  const float* __restrict__ W3, const float* __restrict__ b3,
                  float* __restrict__ scenesR, int nrep)
{
    int b   = blockIdx.y;
    int set = blockIdx.z;
    const float* P = (set == 0) ? P0 : ((set == 1) ? P1 : P2);

    int idx = blockIdx.x * 256 + threadIdx.x;
    if (idx >= NPTS) return;

    const float* p = P + ((size_t)b * NPTS + idx) * 3;
    float px = p[0], py = p[1], pz = p[2];

    const float HI = 14.9999f;  // GZ - 1e-4
    float cx = floorf(fminf(fmaxf(px, 0.0f), HI));
    float cy = floorf(fminf(fmaxf(py, 0.0f), HI));
    float cz = floorf(fminf(fmaxf(pz, 0.0f), HI));

    float x[12];
    x[0] = px - (cx + 0.5f); x[1] = py - (cy + 0.5f); x[2] = pz - (cz + 0.5f);
    x[3] = px - cx;          x[4] = py - cy;          x[5] = pz - cz;
    x[6] = px - (cx + 1.0f); x[7] = py - (cy + 1.0f); x[8] = pz - (cz + 1.0f);
    x[9]  = sqrtf(x[0]*x[0] + x[1]*x[1] + x[2]*x[2]);
    x[10] = sqrtf(x[3]*x[3] + x[4]*x[4] + x[5]*x[5]);
    x[11] = sqrtf(x[6]*x[6] + x[7]*x[7] + x[8]*x[8]);

    float h1[16];
#pragma unroll
    for (int j = 0; j < 16; ++j) {
        float s = b1[j];
#pragma unroll
        for (int k = 0; k < 12; ++k) s = fmaf(x[k], W1[k*16 + j], s);
        h1[j] = eluf(s);
    }
    float h2[16];
#pragma unroll
    for (int j = 0; j < 16; ++j) {
        float s = b2[j];
#pragma unroll
        for (int k = 0; k < 16; ++k) s = fmaf(h1[k], W2[k*16 + j], s);
        h2[j] = eluf(s);
    }
    float o[4];
#pragma unroll
    for (int j = 0; j < 4; ++j) {
        float s = b3[j];
#pragma unroll
        for (int k = 0; k < 16; ++k) s = fmaf(h2[k], W3[k*4 + j], s);
        o[j] = s;
    }

    int cell = (((int)cx) * G + (int)cy) * G + (int)cz;
    int rep  = blockIdx.x & (nrep - 1);
    unsigned* dst = (unsigned*)(scenesR + (size_t)rep * SCENE_FLOATS
                                + (size_t)(b * 12 + set * 4) * G3 + cell);
#pragma unroll
    for (int c = 0; c < 4; ++c) {
        float v = o[c];
        if (v > 0.0f)   // grid floor is 0; positive floats order like uints
            atomicMax(dst + c * G3, __float_as_uint(v));
    }
}

// ---------------------------------------------------------------------------
// Two-level grid barrier: every block does ONE relaxed arrival add; only
// block 0 polls the counter (single poller -> no RMW/load mixing on that
// line); block 0 then stores a per-phase go flag which the other blocks
// poll read-only with long backoff (load-only same-line traffic pipelines
// in TCC). Per-phase counter+flag slots: no reset, no wrap.
// ---------------------------------------------------------------------------
__device__ __forceinline__ void grid_barrier(unsigned* cnt, unsigned* go, int nb) {
    __syncthreads();
    if (threadIdx.x == 0) {
        __builtin_amdgcn_fence(__ATOMIC_RELEASE, "agent");   // wb dirty lines
        __hip_atomic_fetch_add(cnt, 1u, __ATOMIC_RELAXED, __HIP_MEMORY_SCOPE_AGENT);
        if (blockIdx.x == 0) {
            while (__hip_atomic_load(cnt, __ATOMIC_RELAXED, __HIP_MEMORY_SCOPE_AGENT)
                   < (unsigned)nb) {
                __builtin_amdgcn_s_sleep(2);
            }
            __hip_atomic_store(go, 1u, __ATOMIC_RELAXED, __HIP_MEMORY_SCOPE_AGENT);
        } else {
            while (__hip_atomic_load(go, __ATOMIC_RELAXED, __HIP_MEMORY_SCOPE_AGENT)
                   == 0u) {
                __builtin_amdgcn_s_sleep(32);
            }
        }
    }
    __syncthreads();
    __builtin_amdgcn_fence(__ATOMIC_ACQUIRE, "agent");       // one-time inv
}

// ---------------------------------------------------------------------------
// Fused tail: replica max-reduce -> conv1(+stats) -> 6x [BN+ELU+conv](+stats)
// -> final BN+ELU -> d_out.   256 blocks x 256 threads, 8 grid barriers.
// Conv phases: block = (b,co,od); threads = (ciq,oh,ow).
// ---------------------------------------------------------------------------
__global__ __launch_bounds__(256)
void tail_kernel(const float* __restrict__ scenesR, int nrep,
                 float* __restrict__ scenes,
                 const float* __restrict__ conv1_w, const float* __restrict__ conv1_b,
                 const float* __restrict__ bn1_g,   const float* __restrict__ bn1_b,
                 const float* __restrict__ convs_w, const float* __restrict__ convs_b,
                 const float* __restrict__ bns_g,   const float* __restrict__ bns_b,
                 float* __restrict__ yA, float* __restrict__ yB,
                 float* __restrict__ stats,          // 7*16 floats, pre-zeroed
                 unsigned* __restrict__ bar,         // 8 cnt + 8 go, pre-zeroed
                 float* __restrict__ outp)
{
    __shared__ float slab[8 * 5 * 144];   // [ci][kd][12][12] zero-padded
    __shared__ float sscale[8], sshift[8];
    __shared__ float sred[256];

    const int bx  = blockIdx.x;
    const int tid = threadIdx.x;
    const int od = bx & 7, co = (bx >> 3) & 7, b = bx >> 6;
    const int ow = tid & 7, oh = (tid >> 3) & 7, ciq = tid >> 6;
    unsigned* cnt = bar;       // [0..7]
    unsigned* go  = bar + 8;   // [0..7]

    // ---- phase 0: max-reduce replicas -> scenes ---------------------------
    for (int t = bx * 256 + tid; t < SCENE_FLOATS; t += NB_TAIL * 256) {
        float m = 0.0f;
        for (int r = 0; r < nrep; ++r)
            m = fmaxf(m, scenesR[(size_t)r * SCENE_FLOATS + t]);
        scenes[t] = m;
    }
    grid_barrier(cnt + 0, go + 0, NB_TAIL);

    // ---- phase 1: conv1 (stride 2) + stats0 -------------------------------
    {
        float s = 0.0f;
        for (int cin = 0; cin < 3; ++cin) {
            int ci = ciq * 3 + cin;
            const float* sc = scenes + (size_t)(b * 12 + ci) * G3;
            const float* wc = conv1_w + (size_t)(co * 12 + ci) * 125;
#pragma unroll
            for (int kd = 0; kd < 5; ++kd) {
                int id = od * 2 - 2 + kd;
                if ((unsigned)id >= (unsigned)G) continue;   // block-uniform
#pragma unroll
                for (int kh = 0; kh < 5; ++kh) {
                    int ih = oh * 2 - 2 + kh;
                    bool hok = (unsigned)ih < (unsigned)G;
#pragma unroll
                    for (int kw = 0; kw < 5; ++kw) {
                        int iw = ow * 2 - 2 + kw;
                        if (hok && (unsigned)iw < (unsigned)G)
                            s = fmaf(sc[(id * G + ih) * G + iw],
                                     wc[kd*25 + kh*5 + kw], s);
                    }
                }
            }
        }
        sred[tid] = s;
        __syncthreads();
        if (tid < 64) {
            float tot = sred[tid] + sred[64+tid] + sred[128+tid] + sred[192+tid]
                      + conv1_b[co];
            yA[(size_t)(b * 8 + co) * 512 + od * 64 + tid] = tot;
            float sum = tot, sq = tot * tot;
#pragma unroll
            for (int o = 32; o > 0; o >>= 1) {
                sum += __shfl_down(sum, o, 64);
                sq  += __shfl_down(sq,  o, 64);
            }
            if (tid == 0) {
                atomicAdd(&stats[co], sum);
                atomicAdd(&stats[8 + co], sq);
            }
        }
    }

    // ---- phases 2..7: six BN+ELU+conv(stride1) layers ---------------------
    const float* cur = yA;
    float* nxt = yB;
    for (int li = 1; li <= 6; ++li) {
        grid_barrier(cnt + li, go + li, NB_TAIL);

        const float* g   = (li == 1) ? bn1_g : (bns_g + (li - 2) * 8);
        const float* bet = (li == 1) ? bn1_b : (bns_b + (li - 2) * 8);
        const float* sin = stats + (li - 1) * 16;
        const float* w   = convs_w + (size_t)(li - 1) * 8000;

        if (tid < 8) {
            float S = sin[tid], Q = sin[8 + tid];
            float m  = S * (1.0f / 2048.0f);
            float vv = Q * (1.0f / 2048.0f) - m * m;
            float rs = rsqrtf(vv + 1e-5f);
            float sc = g[tid] * rs;
            sscale[tid] = sc;
            sshift[tid] = bet[tid] - m * sc;
        }
        __syncthreads();

        for (int s = tid; s < 5760; s += 256) {
            int ci = s / 720; int r = s % 720;
            int kd = r / 144; int r2 = r % 144;
            int ph = r2 / 12, pw = r2 % 12;
            int id = od - 2 + kd, ih = ph - 2, iw = pw - 2;
            float v = 0.0f;
            if ((unsigned)id < 8u && (unsigned)ih < 8u && (unsigned)iw < 8u) {
                float raw = cur[(size_t)(b * 8 + ci) * 512 + id * 64 + ih * 8 + iw];
                float t = fmaf(raw, sscale[ci], sshift[ci]);
                v = t > 0.0f ? t : __expf(t) - 1.0f;
            }
            slab[s] = v;
        }
        __syncthreads();

        float s = 0.0f;
#pragma unroll
        for (int c2 = 0; c2 < 2; ++c2) {
            int ci = ciq * 2 + c2;
            const float* sl = slab + ci * 720;
            const float* wc = w + (size_t)(co * 8 + ci) * 125;
#pragma unroll
            for (int kd = 0; kd < 5; ++kd) {
#pragma unroll
                for (int kh = 0; kh < 5; ++kh) {
                    const float* row = sl + kd * 144 + (oh + kh) * 12 + ow;
                    const float* wr = wc + kd * 25 + kh * 5;
#pragma unroll
                    for (int kw = 0; kw < 5; ++kw) s = fmaf(row[kw], wr[kw], s);
                }
            }
        }
        sred[tid] = s;
        __syncthreads();
        if (tid < 64) {
            float tot = sred[tid] + sred[64+tid] + sred[128+tid] + sred[192+tid]
                      + convs_b[(li - 1) * 8 + co];
            nxt[(size_t)(b * 8 + co) * 512 + od * 64 + tid] = tot;
            float sum = tot, sq = tot * tot;
#pragma unroll
            for (int o = 32; o > 0; o >>= 1) {
                sum += __shfl_down(sum, o, 64);
                sq  += __shfl_down(sq,  o, 64);
            }
            if (tid == 0) {
                atomicAdd(&stats[li * 16 + co], sum);
                atomicAdd(&stats[li * 16 + 8 + co], sq);
            }
        }
        __syncthreads();
        const float* tmp = cur; cur = nxt; nxt = (float*)tmp;
    }

    // ---- final BN + ELU -> out -------------------------------------------
    grid_barrier(cnt + 7, go + 7, NB_TAIL);
    int i = bx * 256 + tid;
    if (i < 16384) {
        int c = (i >> 9) & 7;
        float S = stats[6 * 16 + c], Q = stats[6 * 16 + 8 + c];
        float m  = S * (1.0f / 2048.0f);
        float vv = Q * (1.0f / 2048.0f) - m * m;
        float rs = rsqrtf(vv + 1e-5f);
        float sc = bns_g[5 * 8 + c] * rs;
        float sh = bns_b[5 * 8 + c] - m * sc;
        float t = fmaf(cur[i], sc, sh);
        outp[i] = t > 0.0f ? t : __expf(t) - 1.0f;
    }
}

// ---------------------------------------------------------------------------
extern "C" void kernel_launch(void* const* d_in, const int* in_sizes, int n_in,
                              void* d_out, int out_size, void* d_ws, size_t ws_size,
                              hipStream_t stream)
{
    const float* goals       = (const float*)d_in[0];
    const float* inputs      = (const float*)d_in[1];
    const float* backgrounds = (const float*)d_in[2];
    const float* W1 = (const float*)d_in[3];
    const float* b1 = (const float*)d_in[4];
    const float* W2 = (const float*)d_in[5];
    const float* b2 = (const float*)d_in[6];
    const float* W3 = (const float*)d_in[7];
    const float* b3 = (const float*)d_in[8];
    const float* conv1_w = (const float*)d_in[9];
    const float* conv1_b = (const float*)d_in[10];
    const float* bn1_g   = (const float*)d_in[11];
    const float* bn1_b   = (const float*)d_in[12];
    const float* convs_w = (const float*)d_in[13];
    const float* convs_b = (const float*)d_in[14];
    const float* bns_g   = (const float*)d_in[15];
    const float* bns_b   = (const float*)d_in[16];

    const size_t need8 = ((size_t)NREP * SCENE_FLOATS + SCENE_FLOATS
                          + 2 * 16384 + 112 + 32) * 4;
    int nrep = (ws_size >= need8) ? NREP : 1;

    float* wsp     = (float*)d_ws;
    float* scenesR = wsp;                                   // nrep * 162000
    float* scenes  = scenesR + (size_t)nrep * SCENE_FLOATS; // 162000
    float* yA      = scenes + SCENE_FLOATS;                 // 16384
    float* yB      = yA + 16384;                            // 16384
    float* stats   = yB + 16384;                            // 7*16 floats
    unsigned* bar  = (unsigned*)(stats + 7 * 16);           // 8 cnt + 8 go

    hipMemsetAsync(scenesR, 0, (size_t)nrep * SCENE_FLOATS * sizeof(float), stream);
    hipMemsetAsync(stats, 0, (7 * 16) * sizeof(float) + 16 * sizeof(unsigned), stream);

    dim3 pgrid((NPTS + 255) / 256, B, 3);
    point_kernel<<<pgrid, 256, 0, stream>>>(inputs, goals, backgrounds,
                                            W1, b1, W2, b2, W3, b3, scenesR, nrep);

    tail_kernel<<<NB_TAIL, 256, 0, stream>>>(scenesR, nrep, scenes,
                                             conv1_w, conv1_b, bn1_g, bn1_b,
                                             convs_w, convs_b, bns_g, bns_b,
                                             yA, yB, stats, bar, (float*)d_out);
}